// Round 4
// baseline (355.648 us; speedup 1.0000x reference)
//
#include <hip/hip_runtime.h>

// out[(b*N + n)*D + c][s] = q[b][s][c] * w[n][c]
// B=8, S=2048, D=256, N=20, fp32 in/out.
// R0: dur = poison-fill (~215 us @ 6.2 TB/s) + kernel (~124 us @ ~2.8 TB/s).
// R2: 4 blocks/CU + nt stores = neutral. R3: 64 KB/wave sequential runs =
// neutral. Fill's own per-wave stream is ALSO strided and runs at ~3 waves/CU
// -> address pattern & concurrency are not the limiter. What differs is
// STRUCTURE: fill is a register-only store burst; ours fed every store
// through LDS round-trip + barrier.
// R4: wave-autonomous register kernel. Wave = one (b,c): 20 w-scales in
// registers, 32 q values gathered once (4B scattered, stride 1 KB; q is
// 16.8 MB -> LLC-resident, each 64B line shared by 16 c-waves), then 160
// register-fed nt stores. No LDS, no barrier, single q pass (16.8 MB reads).
// Discriminates: kernel-structure-bound (expect ~60-80 us kernel) vs
// fill+kernel combined-HBM-bound (expect no change -> roofline).

namespace {
constexpr int kB = 8;
constexpr int kS = 2048;
constexpr int kD = 256;
constexpr int kN = 20;

typedef float v4f __attribute__((ext_vector_type(4)));
}

__global__ __launch_bounds__(256)
void frw_kernel(const float* __restrict__ q, const float* __restrict__ w,
                float* __restrict__ out) {
  const int lane = threadIdx.x & 63;
  const int wv   = threadIdx.x >> 6;
  const int c    = blockIdx.x * 4 + wv;   // wave-uniform channel 0..255
  const int b    = blockIdx.y;            // 0..7

  // Preload the 20 per-class scales for this channel. Wave-uniform address
  // -> one broadcast line per load, L1-hot after first wave.
  float wreg[kN];
#pragma unroll
  for (int n = 0; n < kN; ++n) wreg[n] = w[n * kD + c];

  // Gather this thread's 32 q values: s = 256*k + 4*lane + j, fixed c.
  float qv[8][4];
  const float* qb = q + (size_t)b * kS * kD + c;
#pragma unroll
  for (int k = 0; k < 8; ++k) {
#pragma unroll
    for (int j = 0; j < 4; ++j) {
      qv[k][j] = qb[(size_t)(k * 256 + 4 * lane + j) * kD];
    }
  }

  // 160 register-fed stores: n-outer walks 2 MB apart rows, k-inner walks
  // one 8 KB row in 1 KB wave-contiguous chunks.
  float* ob = out + ((size_t)(b * kN) * kD + (size_t)c) * kS + 4 * lane;
#pragma unroll
  for (int n = 0; n < kN; ++n) {
    const float sc = wreg[n];
    float* orow = ob + (size_t)n * kD * kS;
#pragma unroll
    for (int k = 0; k < 8; ++k) {
      v4f o;
      o.x = qv[k][0] * sc;
      o.y = qv[k][1] * sc;
      o.z = qv[k][2] * sc;
      o.w = qv[k][3] * sc;
      __builtin_nontemporal_store(o, reinterpret_cast<v4f*>(orow + k * 256));
    }
  }
}

extern "C" void kernel_launch(void* const* d_in, const int* in_sizes, int n_in,
                              void* d_out, int out_size, void* d_ws, size_t ws_size,
                              hipStream_t stream) {
  const float* q = (const float*)d_in[0];  // (B, S, D)
  const float* w = (const float*)d_in[1];  // (N, D)
  float* out = (float*)d_out;              // (B*N, D, S)

  dim3 grid(kD / 4, kB, 1);  // 64 x 8 = 512 blocks, 4 waves each
  frw_kernel<<<grid, 256, 0, stream>>>(q, w, out);
}

// Round 5
// 347.248 us; speedup vs baseline: 1.0242x; 1.0242x over previous
//
#include <hip/hip_runtime.h>

// out[(b*N + n)*D + c][s] = q[b][s][c] * w[n][c]
// B=8, S=2048, D=256, N=20, fp32 in/out.
//
// Session decomposition (R0-R4 rocprof):
//   dur ~= poison-fill (1.25 GiB, ~212 us @ 6.3 TB/s, harness-fixed)
//        + ~24 reset dispatches (~60 us, harness-fixed; dispatch-ID spacing
//          between iteration fills is ~25)
//        + frw_kernel (~65-70 us vs 56 us traffic floor: 320 MiB out +
//          16.8 MB q reads @ 6.3 TB/s).
// Nulls that pinned this down: 4 blocks/CU (R2), nt stores (R2), 64 KB
// per-wave sequential runs (R3), register-burst no-LDS structure (R4, -14 us
// regression from its scattered q gather -> kernel time IS visible in dur).
// Kernel-side headroom is <=15 us; everything else is harness-fixed.
//
// This version: R0's best-measured structure (TS=512, TC=16, 512 blocks)
// with the write loops swapped so each LDS tile row is read once into
// registers and reused across all 20 classes (n-major 2 MB store strides;
// R3 proved store address order is free).

namespace {
constexpr int kB = 8;
constexpr int kS = 2048;
constexpr int kD = 256;
constexpr int kN = 20;
constexpr int TS = 512;          // s-tile: 2 KB contiguous per (n,c) row
constexpr int TC = 16;           // c-tile
constexpr int PTS = TS + 4;      // pad: row stride 516 floats breaks pow2
                                 // banking, keeps float4 LDS ops 16B-aligned
}

__global__ __launch_bounds__(256)
void frw_kernel(const float* __restrict__ q, const float* __restrict__ w,
                float* __restrict__ out) {
  const int s0 = blockIdx.x * TS;
  const int c0 = blockIdx.y * TC;
  const int b  = blockIdx.z;
  const int t  = threadIdx.x;

  __shared__ float tile[TC][PTS];  // [c][s]
  __shared__ float ws[kN][TC];

  // Preload 20x16 slice of w (320 floats).
  for (int i = t; i < kN * TC; i += 256) {
    ws[i / TC][i % TC] = w[(i / TC) * kD + c0 + (i % TC)];
  }

  // Load 512(s) x 16(c) tile of q: 4 lanes cover one s-row (64 B contiguous,
  // line-aligned), 256 threads cover 64 s-rows per pass, 8 passes.
  {
    const int lane4 = t & 3;
    const int srow  = t >> 2;        // 0..63
    const int cvec  = lane4 * 4;
#pragma unroll
    for (int k = 0; k < 8; ++k) {
      const int ss = srow + k * 64;
      const float4 v = *reinterpret_cast<const float4*>(
          &q[((size_t)b * kS + (size_t)(s0 + ss)) * kD + (c0 + cvec)]);
      tile[cvec + 0][ss] = v.x;   // 2-way LDS bank aliasing: free
      tile[cvec + 1][ss] = v.y;
      tile[cvec + 2][ss] = v.z;
      tile[cvec + 3][ss] = v.w;
    }
  }
  __syncthreads();

  // Write phase: rg-outer reads each tile row ONCE into registers (float4),
  // n-inner reuses it for all 20 classes. 256 threads x float4 = 2 rows of
  // 512 per rg pass; each wave store = 1 KB contiguous.
  const int half = t >> 7;           // which row of the pair
  const int soff = (t & 127) * 4;    // 0..508
  const size_t nstride = (size_t)kD * kS;  // 2 MiB / 4
#pragma unroll
  for (int rg = 0; rg < TC / 2; ++rg) {
    const int r = rg * 2 + half;
    const float4 v = *reinterpret_cast<const float4*>(&tile[r][soff]);
    size_t op = ((size_t)b * kN * kD + (size_t)(c0 + r)) * kS
                + (size_t)(s0 + soff);
    for (int n = 0; n < kN; ++n) {
      const float sc = ws[n][r];     // wave-uniform -> LDS broadcast
      float4 o;
      o.x = v.x * sc;
      o.y = v.y * sc;
      o.z = v.z * sc;
      o.w = v.w * sc;
      *reinterpret_cast<float4*>(&out[op]) = o;
      op += nstride;
    }
  }
}

extern "C" void kernel_launch(void* const* d_in, const int* in_sizes, int n_in,
                              void* d_out, int out_size, void* d_ws, size_t ws_size,
                              hipStream_t stream) {
  const float* q = (const float*)d_in[0];  // (B, S, D)
  const float* w = (const float*)d_in[1];  // (N, D)
  float* out = (float*)d_out;              // (B*N, D, S)

  dim3 grid(kS / TS, kD / TC, kB);  // 4 x 16 x 8 = 512 blocks
  frw_kernel<<<grid, 256, 0, stream>>>(q, w, out);
}